// Round 1
// baseline (1027.577 us; speedup 1.0000x reference)
//
#include <hip/hip_runtime.h>

// BlockDiagonalChannelAttention: B=4, C=128, H=W=224, PH=PW=7 -> Hh=Ww=32, M=1024, P=49
// One block per patch (bm = b*1024 + hh*32 + ww), 256 threads.

#define CCH 128
#define SF_STR 56    // sF row stride in floats: 7 slots x 8 (7 used) -> 16B-aligned slots
#define SA_STR 136   // sA row stride in bf16: 272B rows -> 16B-aligned, good bank spread

typedef __attribute__((ext_vector_type(8))) unsigned short ushort8v;

static __device__ __forceinline__ unsigned short f2bf(float f) {
    unsigned u = __builtin_bit_cast(unsigned, f);
    u = (u + 0x7FFFu + ((u >> 16) & 1u)) >> 16;   // RNE
    return (unsigned short)u;
}
static __device__ __forceinline__ float bf2f(unsigned short h) {
    return __builtin_bit_cast(float, ((unsigned)h) << 16);
}

__global__ __launch_bounds__(256, 2)
void bdca_kernel(const float* __restrict__ x, const float* __restrict__ betap,
                 float* __restrict__ out, float* __restrict__ sc_out,
                 float* __restrict__ cov_out, float* __restrict__ ec_out)
{
    __shared__ float sF[CCH * SF_STR];            // 28,672 B
    __shared__ unsigned short sA[CCH * SA_STR];   // 34,816 B
    __shared__ float smu[CCH];                    //    512 B   (total 64,000 B)

    const int bm = blockIdx.x;
    const int b  = bm >> 10;
    const int hh = (bm >> 5) & 31;
    const int ww = bm & 31;
    const int t  = threadIdx.x;
    const float beta = betap[0];

    const float* xpatch = x + (size_t)b * (CCH * 50176) + (hh * 7) * 224 + (ww * 7);

    // ---- stage patch into LDS (slot layout) ----
    for (int r = t; r < CCH * 7; r += 256) {
        int c = r / 7, i = r - c * 7;
        const float* src = xpatch + (size_t)c * 50176 + i * 224;
        float* dst = &sF[c * SF_STR + i * 8];
        #pragma unroll
        for (int j = 0; j < 7; ++j) dst[j] = src[j];
    }
    __syncthreads();

    // ---- per-channel mean mu_c ----
    if (t < CCH) {
        const float* row = &sF[t * SF_STR];
        float s = 0.f;
        #pragma unroll
        for (int sl = 0; sl < 7; ++sl) {
            #pragma unroll
            for (int k = 0; k < 7; ++k) s += row[sl * 8 + k];
        }
        smu[t] = s * (1.f / 49.f);
    }
    __syncthreads();

    // ---- G = flat . flat^T, 8x8 register tile per thread, interleaved rows/cols ----
    const int rg = t >> 4;   // rows c = rg + 16*i
    const int cg = t & 15;   // cols d = cg + 16*j
    float g[8][8];
    #pragma unroll
    for (int i = 0; i < 8; ++i)
        #pragma unroll
        for (int j = 0; j < 8; ++j) g[i][j] = 0.f;

    #pragma unroll 1
    for (int sl = 0; sl < 7; ++sl) {
        float bv[8][7];
        #pragma unroll
        for (int j = 0; j < 8; ++j) {
            const float* bp = &sF[(cg + 16 * j) * SF_STR + sl * 8];
            float4 b4 = *(const float4*)bp;
            float2 b2 = *(const float2*)(bp + 4);
            float  b6 = bp[6];
            bv[j][0] = b4.x; bv[j][1] = b4.y; bv[j][2] = b4.z; bv[j][3] = b4.w;
            bv[j][4] = b2.x; bv[j][5] = b2.y; bv[j][6] = b6;
        }
        #pragma unroll
        for (int i = 0; i < 8; ++i) {
            const float* ap = &sF[(rg + 16 * i) * SF_STR + sl * 8];
            float4 a4 = *(const float4*)ap;
            float2 a2 = *(const float2*)(ap + 4);
            float  a6 = ap[6];
            float av[7] = {a4.x, a4.y, a4.z, a4.w, a2.x, a2.y, a6};
            #pragma unroll
            for (int j = 0; j < 8; ++j)
                #pragma unroll
                for (int k = 0; k < 7; ++k)
                    g[i][j] = fmaf(av[k], bv[j][k], g[i][j]);
        }
    }

    // ---- softmax rows (16-lane butterfly), write Sc & cov, stage A=Sc+0.5*cov (bf16) ----
    const size_t scbase = (size_t)bm * (CCH * CCH);
    #pragma unroll
    for (int i = 0; i < 8; ++i) {
        const int c = rg + 16 * i;
        float m = g[i][0];
        #pragma unroll
        for (int j = 1; j < 8; ++j) m = fmaxf(m, g[i][j]);
        #pragma unroll
        for (int msk = 1; msk <= 8; msk <<= 1) m = fmaxf(m, __shfl_xor(m, msk, 64));
        float e[8];
        float s = 0.f;
        #pragma unroll
        for (int j = 0; j < 8; ++j) { e[j] = __expf(g[i][j] - m); s += e[j]; }
        #pragma unroll
        for (int msk = 1; msk <= 8; msk <<= 1) s += __shfl_xor(s, msk, 64);
        const float rinv = 1.f / s;
        const float muc  = smu[c];
        const size_t rowb = scbase + (size_t)c * CCH;
        #pragma unroll
        for (int j = 0; j < 8; ++j) {
            const int d = cg + 16 * j;
            const float sc = e[j] * rinv;
            const float cv = g[i][j] * (1.f / 49.f) - muc * smu[d];
            sc_out[rowb + d]  = sc;
            cov_out[rowb + d] = cv;
            sA[c * SA_STR + d] = f2bf(fmaf(0.5f, cv, sc));
        }
    }
    __syncthreads();

    // ---- Ec = A . flat ; fold + out = x*(beta*Ec + x) ----
    if (t < 224) {
        const int dh  = t & 1;          // d-half (lane pairs)
        const int cg2 = (t >> 1) & 15;  // rows c = cg2 + 16*i
        const int pg  = t >> 5;         // 0..6 : patch row i, cols p = pg*7 + k
        const int d0  = dh * 64;
        float acc[8][7];
        #pragma unroll
        for (int i = 0; i < 8; ++i)
            #pragma unroll
            for (int k = 0; k < 7; ++k) acc[i][k] = 0.f;

        #pragma unroll 1
        for (int jc = 0; jc < 8; ++jc) {
            const int d = d0 + jc * 8;
            ushort8v av[8];
            #pragma unroll
            for (int i = 0; i < 8; ++i)
                av[i] = *(const ushort8v*)&sA[(cg2 + 16 * i) * SA_STR + d];
            #pragma unroll
            for (int q = 0; q < 8; ++q) {
                const float* fp = &sF[(d + q) * SF_STR + pg * 8];
                float4 f4 = *(const float4*)fp;
                float2 f2 = *(const float2*)(fp + 4);
                float  f6 = fp[6];
                float fv[7] = {f4.x, f4.y, f4.z, f4.w, f2.x, f2.y, f6};
                #pragma unroll
                for (int i = 0; i < 8; ++i) {
                    const float aval = bf2f(av[i][q]);
                    #pragma unroll
                    for (int k = 0; k < 7; ++k)
                        acc[i][k] = fmaf(aval, fv[k], acc[i][k]);
                }
            }
        }
        // combine the two d-halves (partner lane = lane^1)
        #pragma unroll
        for (int i = 0; i < 8; ++i)
            #pragma unroll
            for (int k = 0; k < 7; ++k)
                acc[i][k] += __shfl_xor(acc[i][k], 1, 64);

        // each partner writes 4 of the 8 c-rows
        #pragma unroll
        for (int i = 0; i < 8; ++i) {
            if ((i >> 2) == dh) {
                const int c = cg2 + 16 * i;
                const float* xrow = &sF[c * SF_STR + pg * 8];
                const size_t gaddr =
                    ((size_t)(b * CCH + c) * 224 + (hh * 7 + pg)) * 224 + (ww * 7);
                #pragma unroll
                for (int k = 0; k < 7; ++k) {
                    const float ec = acc[i][k];
                    const float xv = xrow[k];
                    ec_out[gaddr + k] = ec;
                    out[gaddr + k]    = xv * fmaf(beta, ec, xv);
                }
            }
        }
    }
}

extern "C" void kernel_launch(void* const* d_in, const int* in_sizes, int n_in,
                              void* d_out, int out_size, void* d_ws, size_t ws_size,
                              hipStream_t stream)
{
    const float* x    = (const float*)d_in[0];
    const float* beta = (const float*)d_in[1];
    float* out = (float*)d_out;
    float* sc  = out + 25690112;   // 4*128*224*224
    float* cov = sc  + 67108864;   // 4*1024*128*128
    float* ec  = cov + 67108864;
    bdca_kernel<<<dim3(4096), dim3(256), 0, stream>>>(x, beta, out, sc, cov, ec);
}